// Round 9
// baseline (592.422 us; speedup 1.0000x reference)
//
#include <hip/hip_runtime.h>
#include <hip/hip_fp16.h>
#include <math.h>

constexpr int NN  = 50000;   // nodes
constexpr int EE  = 800000;  // edges
constexpr int INF_ = 256;    // input feat
constexpr int HF  = 128;     // hidden
constexpr int CC  = 50;      // classes
constexpr long NH = (long)NN * HF;
constexpr int NSL = 32;          // edge slices (preprocessing)
constexpr int ESL = EE / NSL;    // 25000 edges per slice
constexpr int CHK = 12500;       // nodes per chunk (4 chunks), 50KB LDS
#define EPSV 1e-5f

enum { EPI_RELU = 0, EPI_NONE = 1, EPI_BN = 2, EPI_BN_RES = 3 };
enum { H16_NONE = 0, H16_RAW = 1, H16_SCALED = 2 };

typedef __attribute__((ext_vector_type(4))) float f32x4;
typedef __attribute__((ext_vector_type(8))) short bf16x8;

__device__ __forceinline__ ushort f2bf(float f) {
  union { float f; unsigned u; } v; v.f = f;
  unsigned r = (v.u + 0x7fffu + ((v.u >> 16) & 1u)) >> 16;  // RNE
  return (ushort)r;
}
__device__ __forceinline__ float bf2f(ushort u) {
  union { unsigned u; float f; } v; v.u = ((unsigned)u) << 16;
  return v.f;
}

// ---------------- graph preprocessing (atomic-free: LDS histograms) ----------------

__global__ __launch_bounds__(256) void count_partial_kernel(
    const int4* __restrict__ keys4, unsigned* __restrict__ partials) {
  __shared__ unsigned cnt[CHK];
  const int chunk = blockIdx.x & 3;
  const int sl = blockIdx.x >> 2;
  for (int i = threadIdx.x; i < CHK; i += 256) cnt[i] = 0;
  __syncthreads();
  const int base4 = sl * (ESL / 4);
  const int lo = chunk * CHK;
  for (int i = threadIdx.x; i < ESL / 4; i += 256) {
    int4 k = keys4[base4 + i];
    int a;
    a = k.x - lo; if ((unsigned)a < (unsigned)CHK) atomicAdd(&cnt[a], 1u);
    a = k.y - lo; if ((unsigned)a < (unsigned)CHK) atomicAdd(&cnt[a], 1u);
    a = k.z - lo; if ((unsigned)a < (unsigned)CHK) atomicAdd(&cnt[a], 1u);
    a = k.w - lo; if ((unsigned)a < (unsigned)CHK) atomicAdd(&cnt[a], 1u);
  }
  __syncthreads();
  unsigned* p = partials + (long)sl * NN + lo;
  for (int i = threadIdx.x; i < CHK; i += 256) p[i] = cnt[i];
}

__global__ __launch_bounds__(256) void reduce_deg_kernel(
    const unsigned* __restrict__ pd, const unsigned* __restrict__ ps,
    int* __restrict__ indeg, float* __restrict__ inv_mean,
    float* __restrict__ inv_in, float* __restrict__ inv_out) {
  int n = blockIdx.x * 256 + threadIdx.x;
  if (n >= NN) return;
  unsigned di = 0, dz = 0;
  #pragma unroll 8
  for (int sl = 0; sl < NSL; ++sl) {
    di += pd[(long)sl * NN + n];
    dz += ps[(long)sl * NN + n];
  }
  indeg[n] = (int)di;
  float fdi = fmaxf((float)di, 1.f), fdz = fmaxf((float)dz, 1.f);
  inv_mean[n] = 1.f / fdi;
  inv_in[n]  = rsqrtf(fdi);
  inv_out[n] = rsqrtf(fdz);
}

__global__ __launch_bounds__(256) void scan_block_kernel(const int* __restrict__ counts,
                                                         int* excl, int* bsum, int n) {
  __shared__ int sh[256];
  int i = blockIdx.x * 256 + threadIdx.x;
  int v = (i < n) ? counts[i] : 0;
  sh[threadIdx.x] = v;
  __syncthreads();
  #pragma unroll
  for (int off = 1; off < 256; off <<= 1) {
    int tv = (threadIdx.x >= off) ? sh[threadIdx.x - off] : 0;
    __syncthreads();
    sh[threadIdx.x] += tv;
    __syncthreads();
  }
  if (i < n) excl[i] = sh[threadIdx.x] - v;
  if (threadIdx.x == 255 && bsum) bsum[blockIdx.x] = sh[255];
}

// builds per-(slice,node) cursors AND packed nodeinfo {e0, end, inv_mean, inv_in}
__global__ void cursor_init_kernel(const int* __restrict__ row_ptr, const int* __restrict__ bsum,
                                   const unsigned* __restrict__ pd,
                                   unsigned* __restrict__ cur0,
                                   const float* __restrict__ inv_mean,
                                   const float* __restrict__ inv_in,
                                   int4* __restrict__ nodeinfo) {
  int n = blockIdx.x * 256 + threadIdx.x;
  if (n >= NN) return;
  unsigned start = (unsigned)(row_ptr[n] + bsum[n >> 8]);
  unsigned run = start;
  #pragma unroll 8
  for (int sl = 0; sl < NSL; ++sl) {
    cur0[(long)sl * NN + n] = run;
    run += pd[(long)sl * NN + n];
  }
  nodeinfo[n] = make_int4((int)start, (int)run,
                          __float_as_int(inv_mean[n]), __float_as_int(inv_in[n]));
}

__global__ __launch_bounds__(256) void fill_partial_kernel(
    const int4* __restrict__ dst4, const int4* __restrict__ src4,
    const unsigned* __restrict__ cur0, int* __restrict__ col) {
  __shared__ unsigned cur[CHK];
  const int chunk = blockIdx.x & 3;
  const int sl = blockIdx.x >> 2;
  const int lo = chunk * CHK;
  const unsigned* c0 = cur0 + (long)sl * NN + lo;
  for (int i = threadIdx.x; i < CHK; i += 256) cur[i] = c0[i];
  __syncthreads();
  const int base4 = sl * (ESL / 4);
  for (int i = threadIdx.x; i < ESL / 4; i += 256) {
    int4 d = dst4[base4 + i];
    int4 s = src4[base4 + i];
    int a;
    a = d.x - lo; if ((unsigned)a < (unsigned)CHK) col[atomicAdd(&cur[a], 1u)] = s.x;
    a = d.y - lo; if ((unsigned)a < (unsigned)CHK) col[atomicAdd(&cur[a], 1u)] = s.y;
    a = d.z - lo; if ((unsigned)a < (unsigned)CHK) col[atomicAdd(&cur[a], 1u)] = s.z;
    a = d.w - lo; if ((unsigned)a < (unsigned)CHK) col[atomicAdd(&cur[a], 1u)] = s.w;
  }
}

// ---------------- SpMM over feature-sliced fp16 table (32-feat slices) ----------------
// Output written as bf16 hi/lo ushort pairs (row-major [node][128]).

__global__ __launch_bounds__(256) void spmm32s_kernel(
    const int4* __restrict__ nodeinfo, const int* __restrict__ cols,
    const __half* __restrict__ xs, int useW,
    ushort* __restrict__ outh, ushort* __restrict__ outl) {
  const int t = threadIdx.x;
  const int lane = t & 63;
  const int wv = t >> 6;
  const int b = blockIdx.x;
  const int xcd = b & 7;
  const int slice = xcd >> 1;
  const int sub = xcd & 1;
  const int node = (b >> 3) * 8 + wv * 2 + sub;   // exact cover: NN = 6250*8
  const int q8 = lane & 7;       // feature quarter: 4 halfs (8B)
  const int e8 = lane >> 3;      // edge slot within group of 8
  const __half* xb = xs + (long)slice * NN * 32 + q8 * 4;
  int4 ni = nodeinfo[node];
  const int e0 = ni.x, end = ni.y;
  const float d = __int_as_float(useW ? ni.w : ni.z);
  const int end1 = end - 1;
  float a0 = 0.f, a1 = 0.f, a2 = 0.f, a3 = 0.f;
  float c0 = 0.f, c1 = 0.f, c2 = 0.f, c3 = 0.f;
  for (int e = e0; e < end; e += 16) {
    int ee0 = e + e8;
    int ee1 = ee0 + 8;
    int ec0 = ee0 < end ? ee0 : end1;
    int ec1 = ee1 < end ? ee1 : end1;
    int s0 = cols[ec0];
    int s1 = cols[ec1];
    float m0 = ee0 < end ? 1.f : 0.f;
    float m1 = ee1 < end ? 1.f : 0.f;
    float2 v0 = *(const float2*)(xb + (unsigned)s0 * 32u);
    float2 v1 = *(const float2*)(xb + (unsigned)s1 * 32u);
    const __half2* h0 = (const __half2*)&v0;
    const __half2* h1 = (const __half2*)&v1;
    float2 f00 = __half22float2(h0[0]), f01 = __half22float2(h0[1]);
    float2 f10 = __half22float2(h1[0]), f11 = __half22float2(h1[1]);
    a0 = fmaf(f00.x, m0, a0); a1 = fmaf(f00.y, m0, a1);
    a2 = fmaf(f01.x, m0, a2); a3 = fmaf(f01.y, m0, a3);
    c0 = fmaf(f10.x, m1, c0); c1 = fmaf(f10.y, m1, c1);
    c2 = fmaf(f11.x, m1, c2); c3 = fmaf(f11.y, m1, c3);
  }
  a0 += c0; a1 += c1; a2 += c2; a3 += c3;
  #pragma unroll
  for (int m = 8; m < 64; m <<= 1) {
    a0 += __shfl_xor(a0, m, 64);
    a1 += __shfl_xor(a1, m, 64);
    a2 += __shfl_xor(a2, m, 64);
    a3 += __shfl_xor(a3, m, 64);
  }
  if (lane < 8) {
    a0 *= d; a1 *= d; a2 *= d; a3 *= d;
    ushort h0 = f2bf(a0), h1 = f2bf(a1), h2 = f2bf(a2), h3 = f2bf(a3);
    ushort l0 = f2bf(a0 - bf2f(h0)), l1 = f2bf(a1 - bf2f(h1));
    ushort l2 = f2bf(a2 - bf2f(h2)), l3 = f2bf(a3 - bf2f(h3));
    long base = (long)node * HF + slice * 32 + q8 * 4;
    *(ushort4*)(outh + base) = make_ushort4(h0, h1, h2, h3);
    *(ushort4*)(outl + base) = make_ushort4(l0, l1, l2, l3);
  }
}

// ---------------- attention gate + gated residual (reads hi/lo activations) ----------------

__global__ __launch_bounds__(128) void attn_hatt_kernel(
    const float* __restrict__ a, const float* __restrict__ w2, const float* __restrict__ b2,
    const ushort* __restrict__ h0h, const ushort* __restrict__ h0l,
    const ushort* __restrict__ agh, const ushort* __restrict__ agl,
    const float* __restrict__ inv_out,
    __half* __restrict__ hatt16) {
  int r = blockIdx.x, f = threadIdx.x;
  long idx = (long)r * HF + f;
  float v = a[idx] * w2[f];
  #pragma unroll
  for (int off = 32; off >= 1; off >>= 1) v += __shfl_down(v, off, 64);
  __shared__ float red[2];
  if ((f & 63) == 0) red[f >> 6] = v;
  __syncthreads();
  float dot = red[0] + red[1] + b2[0];
  float s = 1.f / (1.f + __expf(-dot));
  float h0v = bf2f(h0h[idx]) + bf2f(h0l[idx]);
  float agv = bf2f(agh[idx]) + bf2f(agl[idx]);
  float h = h0v + agv * s;
  hatt16[((long)(f >> 5) * NN + r) * 32 + (f & 31)] = __float2half(h * inv_out[r]);
}

// ---------------- weight prepack: fp32 W[K][N] -> bf16 hi/lo MFMA fragments ----------------

__global__ void prepack_kernel(const float* __restrict__ W, int N, int ldw, int NTpad,
                               ushort* __restrict__ hi, ushort* __restrict__ lo, int total) {
  int idx = blockIdx.x * 256 + threadIdx.x;
  if (idx >= total) return;
  int j    = idx & 7;
  int lane = (idx >> 3) & 63;
  int rest = idx >> 9;
  int nt = rest % NTpad;
  int kc = rest / NTpad;
  int k = kc * 32 + (lane >> 4) * 8 + j;
  int n = nt * 16 + (lane & 15);
  float w = (n < N) ? W[(long)k * ldw + n] : 0.f;
  ushort h = f2bf(w);
  hi[idx] = h;
  lo[idx] = f2bf(w - bf2f(h));
}

// ---------------- split-bf16 MFMA GEMM: out = epi( [A1|A2] @ W + bias ) ----------------
// ASRC=0: A fp32, split in-loop (features). ASRC=1: A is bf16 hi/lo ushort pair.
// OUTM=0: fp32 out. OUTM=1: bf16 hi/lo out.

template<int KC, int NT, int EPI, int H16, int ASRC, int OUTM>
__global__ __launch_bounds__(256) void mgemm_kernel(
    const void* __restrict__ A1a, const void* __restrict__ A1b, int lda1,
    const void* __restrict__ A2a, const void* __restrict__ A2b, int lda2,
    const ushort* __restrict__ Bhi, const ushort* __restrict__ Blo,
    const float* __restrict__ bias,
    const float* __restrict__ g, const float* __restrict__ be,
    const float* __restrict__ mu, const float* __restrict__ va,
    const ushort* __restrict__ resh, const ushort* __restrict__ resl,
    float* __restrict__ outf, int ldc, int Ncols,
    ushort* __restrict__ outh, ushort* __restrict__ outl,
    __half* __restrict__ out16, const float* __restrict__ rowscale) {
  const int t = threadIdx.x;
  const int lane = t & 63;
  const int wid = t >> 6;
  const int rowbase = blockIdx.x * 128 + wid * 32;
  const int arow0 = rowbase + (lane & 15);
  const int arow1 = arow0 + 16;
  const int kgrp = (lane >> 4) * 8;

  f32x4 acc[2][NT];
  #pragma unroll
  for (int r = 0; r < 2; ++r)
    #pragma unroll
    for (int n = 0; n < NT; ++n) acc[r][n] = (f32x4){0.f, 0.f, 0.f, 0.f};

  for (int kc = 0; kc < KC; ++kc) {
    const bool second = (KC == 8) && (kc >= 4);
    bf16x8 ah0, al0, ah1, al1;
    const bf16x8 z8 = (bf16x8){0, 0, 0, 0, 0, 0, 0, 0};
    ah0 = al0 = ah1 = al1 = z8;

    if (ASRC == 0) {
      const float* Ap = (const float*)(second ? A2a : A1a);
      const int lda = second ? lda2 : lda1;
      const long kb = (long)(second ? (kc - 4) * 32 : kc * 32) + kgrp;
      const f32x4 z4 = {0.f, 0.f, 0.f, 0.f};
      f32x4 av0a = z4, av0b = z4, av1a = z4, av1b = z4;
      if (arow0 < NN) {
        const float* p = Ap + (long)arow0 * lda + kb;
        av0a = *(const f32x4*)p;
        av0b = *(const f32x4*)(p + 4);
      }
      if (arow1 < NN) {
        const float* p = Ap + (long)arow1 * lda + kb;
        av1a = *(const f32x4*)p;
        av1b = *(const f32x4*)(p + 4);
      }
      #pragma unroll
      for (int j = 0; j < 8; ++j) {
        float v0 = (j < 4) ? av0a[j] : av0b[j - 4];
        ushort h0 = f2bf(v0);
        ah0[j] = (short)h0;
        al0[j] = (short)f2bf(v0 - bf2f(h0));
        float v1 = (j < 4) ? av1a[j] : av1b[j - 4];
        ushort h1 = f2bf(v1);
        ah1[j] = (short)h1;
        al1[j] = (short)f2bf(v1 - bf2f(h1));
      }
    } else {
      const ushort* Ah = (const ushort*)(second ? A2a : A1a);
      const ushort* Al = (const ushort*)(second ? A2b : A1b);
      const int lda = second ? lda2 : lda1;
      const long kb = (long)(second ? (kc - 4) * 32 : kc * 32) + kgrp;
      if (arow0 < NN) {
        long o = (long)arow0 * lda + kb;
        ah0 = *(const bf16x8*)(Ah + o);
        al0 = *(const bf16x8*)(Al + o);
      }
      if (arow1 < NN) {
        long o = (long)arow1 * lda + kb;
        ah1 = *(const bf16x8*)(Ah + o);
        al1 = *(const bf16x8*)(Al + o);
      }
    }

    const ushort* bh = Bhi + ((long)kc * NT * 64 + lane) * 8;
    const ushort* bl = Blo + ((long)kc * NT * 64 + lane) * 8;
    #pragma unroll
    for (int nt = 0; nt < NT; ++nt) {
      bf16x8 bhv = *(const bf16x8*)(bh + (long)nt * 512);
      bf16x8 blv = *(const bf16x8*)(bl + (long)nt * 512);
      acc[0][nt] = __builtin_amdgcn_mfma_f32_16x16x32_bf16(ah0, bhv, acc[0][nt], 0, 0, 0);
      acc[1][nt] = __builtin_amdgcn_mfma_f32_16x16x32_bf16(ah1, bhv, acc[1][nt], 0, 0, 0);
      acc[0][nt] = __builtin_amdgcn_mfma_f32_16x16x32_bf16(al0, bhv, acc[0][nt], 0, 0, 0);
      acc[1][nt] = __builtin_amdgcn_mfma_f32_16x16x32_bf16(al1, bhv, acc[1][nt], 0, 0, 0);
      acc[0][nt] = __builtin_amdgcn_mfma_f32_16x16x32_bf16(ah0, blv, acc[0][nt], 0, 0, 0);
      acc[1][nt] = __builtin_amdgcn_mfma_f32_16x16x32_bf16(ah1, blv, acc[1][nt], 0, 0, 0);
    }
  }

  const int colg = lane & 15;
  const int rsub = (lane >> 4) * 4;
  #pragma unroll
  for (int nt = 0; nt < NT; ++nt) {
    int c = nt * 16 + colg;
    if (c >= Ncols) continue;
    float bb = bias ? bias[c] : 0.f;
    float scale = 1.f, shift = 0.f;
    if (EPI == EPI_BN || EPI == EPI_BN_RES) {
      scale = g[c] * rsqrtf(va[c] + EPSV);
      shift = be[c] - mu[c] * scale;
    }
    #pragma unroll
    for (int rg = 0; rg < 2; ++rg) {
      #pragma unroll
      for (int i = 0; i < 4; ++i) {
        int r = rowbase + rg * 16 + rsub + i;
        if (r >= NN) continue;
        long ridx = (long)r * HF + c;
        float v = acc[rg][nt][i] + bb;
        if (EPI == EPI_RELU) {
          v = fmaxf(v, 0.f);
        } else if (EPI == EPI_BN || EPI == EPI_BN_RES) {
          v = fmaxf(v * scale + shift, 0.f);
          if (EPI == EPI_BN_RES) v += bf2f(resh[ridx]) + bf2f(resl[ridx]);
        }
        if (OUTM == 0) {
          outf[(long)r * ldc + c] = v;
        } else {
          ushort hh = f2bf(v);
          outh[ridx] = hh;
          outl[ridx] = f2bf(v - bf2f(hh));
        }
        if (H16 != H16_NONE) {
          float sc = (H16 == H16_SCALED) ? rowscale[r] : 1.f;
          out16[((long)(nt >> 1) * NN + r) * 32 + (nt & 1) * 16 + colg] = __float2half(v * sc);
        }
      }
    }
  }
}

// ---------------- launch ----------------

extern "C" void kernel_launch(void* const* d_in, const int* in_sizes, int n_in,
                              void* d_out, int out_size, void* d_ws, size_t ws_size,
                              hipStream_t stream) {
  const float* features = (const float*)d_in[0];
  const int*   src      = (const int*)d_in[1];
  const int*   dst      = (const int*)d_in[2];
  const float* w_in     = (const float*)d_in[3];
  const float* b_in     = (const float*)d_in[4];
  const float* gc_w     = (const float*)d_in[5];
  const float* gc_b     = (const float*)d_in[6];
  const float* bn_gamma = (const float*)d_in[7];
  const float* bn_beta  = (const float*)d_in[8];
  const float* bn_mean  = (const float*)d_in[9];
  const float* bn_var   = (const float*)d_in[10];
  const float* attn_w1  = (const float*)d_in[11];
  const float* attn_b1  = (const float*)d_in[12];
  const float* attn_w2  = (const float*)d_in[13];
  const float* attn_b2  = (const float*)d_in[14];
  const float* agg_w    = (const float*)d_in[15];
  const float* agg_b    = (const float*)d_in[16];
  const float* out_w    = (const float*)d_in[17];
  const float* out_b    = (const float*)d_in[18];
  float* out = (float*)d_out;

  float* fbase = (float*)d_ws;
  float* Af = fbase;                     // NH floats: attn 'a' (fp32, single consumer)
  float* inv_mean = fbase + NH;
  float* inv_in   = inv_mean + NN;
  float* inv_out  = inv_in + NN;
  int* indeg   = (int*)(inv_out + NN);   // NN
  int* row_ptr = indeg + NN;             // NN+16 (padded)
  int* bsum    = row_ptr + NN + 16;      // 256
  int* col     = bsum + 256;             // EE
  int4* nodeinfo = (int4*)(col + EE);    // NN int4

  // preprocessing scratch aliased into Af (dead before Af's first write)
  unsigned* pd   = (unsigned*)Af;             // NSL*NN
  unsigned* ps   = pd + (long)NSL * NN;
  unsigned* cur0 = ps + (long)NSL * NN;

  // packed bf16 hi/lo weights
  ushort* pk = (ushort*)(nodeinfo + NN);
  const int SZ256 = 8 * 8 * 512;     // K=256, NT=8
  const int SZ128 = 4 * 8 * 512;     // K=128, NT=8
  const int SZOUT = 4 * 4 * 512;     // K=128, NT=4
  ushort* win_hi = pk;  pk += SZ256;  ushort* win_lo = pk;  pk += SZ256;
  ushort* agg_hi = pk;  pk += SZ256;  ushort* agg_lo = pk;  pk += SZ256;
  ushort* at1_hi = pk;  pk += SZ256;  ushort* at1_lo = pk;  pk += SZ256;
  ushort* gch[3], *gcl[3];
  for (int i = 0; i < 3; ++i) { gch[i] = pk; pk += SZ128; gcl[i] = pk; pk += SZ128; }
  ushort* ow_hi = pk;  pk += SZOUT;   ushort* ow_lo = pk;  pk += SZOUT;

  // activation pools (bf16 hi/lo pairs, row-major [node][128]) + fp16 gather table
  ushort* P0h = pk;        pk += NH;   ushort* P0l = pk;  pk += NH;  // h0 -> h3
  ushort* P1h = pk;        pk += NH;   ushort* P1l = pk;  pk += NH;  // neigh -> h1
  ushort* P2h = pk;        pk += NH;   ushort* P2l = pk;  pk += NH;  // agg -> h2
  ushort* P3h = pk;        pk += NH;   ushort* P3l = pk;  pk += NH;  // spmm rst
  __half* X16 = (__half*)pk;           // NH halfs, sliced [4][NN][32]

  dim3 b256(256), b128(128);
  const int gN = (NN + 255) / 256;
  const int gblocks = (NN + 127) / 128;
  const int gspmm = (NN / 8) * 8;
  const int gpre = NSL * 4;

  // graph preprocessing (no global atomics)
  count_partial_kernel<<<gpre, b256, 0, stream>>>((const int4*)dst, pd);
  count_partial_kernel<<<gpre, b256, 0, stream>>>((const int4*)src, ps);
  reduce_deg_kernel<<<gN, b256, 0, stream>>>(pd, ps, indeg, inv_mean, inv_in, inv_out);
  scan_block_kernel<<<gN, b256, 0, stream>>>(indeg, row_ptr, bsum, NN);
  scan_block_kernel<<<1, b256, 0, stream>>>(bsum, bsum, nullptr, gN);
  cursor_init_kernel<<<gN, b256, 0, stream>>>(row_ptr, bsum, pd, cur0, inv_mean, inv_in, nodeinfo);
  fill_partial_kernel<<<gpre, b256, 0, stream>>>((const int4*)dst, (const int4*)src, cur0, col);

  // weight prepack
  prepack_kernel<<<(SZ256 + 255) / 256, b256, 0, stream>>>(w_in,    HF, HF, 8, win_hi, win_lo, SZ256);
  prepack_kernel<<<(SZ256 + 255) / 256, b256, 0, stream>>>(agg_w,   HF, HF, 8, agg_hi, agg_lo, SZ256);
  prepack_kernel<<<(SZ256 + 255) / 256, b256, 0, stream>>>(attn_w1, HF, HF, 8, at1_hi, at1_lo, SZ256);
  for (int i = 0; i < 3; ++i)
    prepack_kernel<<<(SZ128 + 255) / 256, b256, 0, stream>>>(gc_w + (long)i * HF * HF, HF, HF, 8, gch[i], gcl[i], SZ128);
  prepack_kernel<<<(SZOUT + 255) / 256, b256, 0, stream>>>(out_w, CC, CC, 4, ow_hi, ow_lo, SZOUT);

  // #1: h0 = relu(features @ w_in + b_in)  -> P0 (hi/lo) + X16 raw
  mgemm_kernel<8, 8, EPI_RELU, H16_RAW, 0, 1><<<gblocks, b256, 0, stream>>>(
      features, nullptr, INF_, features + 128, nullptr, INF_, win_hi, win_lo, b_in,
      nullptr, nullptr, nullptr, nullptr, nullptr, nullptr,
      nullptr, HF, HF, P0h, P0l, X16, nullptr);
  // spmm#1: neigh = mean-agg(h0) -> P1
  spmm32s_kernel<<<gspmm, b256, 0, stream>>>(nodeinfo, col, X16, 0, P1h, P1l);
  // #2: agg = relu([h0|neigh] @ agg_w + agg_b) -> P2
  mgemm_kernel<8, 8, EPI_RELU, H16_NONE, 1, 1><<<gblocks, b256, 0, stream>>>(
      P0h, P0l, HF, P1h, P1l, HF, agg_hi, agg_lo, agg_b,
      nullptr, nullptr, nullptr, nullptr, nullptr, nullptr,
      nullptr, HF, HF, P2h, P2l, nullptr, nullptr);
  // #3: a = relu([h0|agg] @ attn_w1 + attn_b1) -> Af (fp32)
  mgemm_kernel<8, 8, EPI_RELU, H16_NONE, 1, 0><<<gblocks, b256, 0, stream>>>(
      P0h, P0l, HF, P2h, P2l, HF, at1_hi, at1_lo, attn_b1,
      nullptr, nullptr, nullptr, nullptr, nullptr, nullptr,
      Af, HF, HF, nullptr, nullptr, nullptr, nullptr);
  // attn: h_att = h0 + agg * sigmoid(a@w2+b2) -> X16 (scaled by inv_out)
  attn_hatt_kernel<<<NN, b128, 0, stream>>>(Af, attn_w2, attn_b2, P0h, P0l, P2h, P2l, inv_out, X16);

  // layer 0: spmm -> P3 ; relu(BN(P3@gc0+b0)) -> P1 + X16
  spmm32s_kernel<<<gspmm, b256, 0, stream>>>(nodeinfo, col, X16, 1, P3h, P3l);
  mgemm_kernel<4, 8, EPI_BN, H16_SCALED, 1, 1><<<gblocks, b256, 0, stream>>>(
      P3h, P3l, HF, nullptr, nullptr, 0, gch[0], gcl[0], gc_b,
      bn_gamma, bn_beta, bn_mean, bn_var, nullptr, nullptr,
      nullptr, HF, HF, P1h, P1l, X16, inv_out);
  // layer 1: spmm -> P3 ; relu(BN(P3@gc1+b1)) + h1 -> P2 + X16
  spmm32s_kernel<<<gspmm, b256, 0, stream>>>(nodeinfo, col, X16, 1, P3h, P3l);
  mgemm_kernel<4, 8, EPI_BN_RES, H16_SCALED, 1, 1><<<gblocks, b256, 0, stream>>>(
      P3h, P3l, HF, nullptr, nullptr, 0, gch[1], gcl[1], gc_b + HF,
      bn_gamma + HF, bn_beta + HF, bn_mean + HF, bn_var + HF, P1h, P1l,
      nullptr, HF, HF, P2h, P2l, X16, inv_out);
  // layer 2: spmm -> P3 ; relu(BN(P3@gc2+b2)) + h2 -> P0
  spmm32s_kernel<<<gspmm, b256, 0, stream>>>(nodeinfo, col, X16, 1, P3h, P3l);
  mgemm_kernel<4, 8, EPI_BN_RES, H16_NONE, 1, 1><<<gblocks, b256, 0, stream>>>(
      P3h, P3l, HF, nullptr, nullptr, 0, gch[2], gcl[2], gc_b + 2 * HF,
      bn_gamma + 2 * HF, bn_beta + 2 * HF, bn_mean + 2 * HF, bn_var + 2 * HF, P2h, P2l,
      nullptr, HF, HF, P0h, P0l, nullptr, nullptr);

  // #7: out = h3 @ out_w + out_b -> d_out
  mgemm_kernel<4, 4, EPI_NONE, H16_NONE, 1, 0><<<gblocks, b256, 0, stream>>>(
      P0h, P0l, HF, nullptr, nullptr, 0, ow_hi, ow_lo, out_b,
      nullptr, nullptr, nullptr, nullptr, nullptr, nullptr,
      out, CC, CC, nullptr, nullptr, nullptr, nullptr);
}

// Round 10
// 427.253 us; speedup vs baseline: 1.3866x; 1.3866x over previous
//
#include <hip/hip_runtime.h>
#include <hip/hip_fp16.h>
#include <math.h>

constexpr int NN  = 50000;   // nodes
constexpr int EE  = 800000;  // edges
constexpr int INF_ = 256;    // input feat
constexpr int HF  = 128;     // hidden
constexpr int CC  = 50;      // classes
constexpr long NH = (long)NN * HF;
constexpr int NSL = 32;          // edge slices (preprocessing)
constexpr int ESL = EE / NSL;    // 25000 edges per slice
constexpr int CHK = 12500;       // nodes per chunk (4 chunks), 50KB LDS
#define EPSV 1e-5f

enum { EPI_RELU = 0, EPI_NONE = 1, EPI_BN = 2, EPI_BN_RES = 3 };
enum { H16_NONE = 0, H16_RAW = 1, H16_SCALED = 2 };

typedef __attribute__((ext_vector_type(4))) float f32x4;
typedef __attribute__((ext_vector_type(8))) short bf16x8;

__device__ __forceinline__ ushort f2bf(float f) {
  union { float f; unsigned u; } v; v.f = f;
  unsigned r = (v.u + 0x7fffu + ((v.u >> 16) & 1u)) >> 16;  // RNE
  return (ushort)r;
}
__device__ __forceinline__ float bf2f(ushort u) {
  union { unsigned u; float f; } v; v.u = ((unsigned)u) << 16;
  return v.f;
}

// ---------------- graph preprocessing (atomic-free: LDS histograms) ----------------

__global__ __launch_bounds__(256) void count_partial_kernel(
    const int4* __restrict__ keys4, unsigned* __restrict__ partials) {
  __shared__ unsigned cnt[CHK];
  const int chunk = blockIdx.x & 3;
  const int sl = blockIdx.x >> 2;
  for (int i = threadIdx.x; i < CHK; i += 256) cnt[i] = 0;
  __syncthreads();
  const int base4 = sl * (ESL / 4);
  const int lo = chunk * CHK;
  for (int i = threadIdx.x; i < ESL / 4; i += 256) {
    int4 k = keys4[base4 + i];
    int a;
    a = k.x - lo; if ((unsigned)a < (unsigned)CHK) atomicAdd(&cnt[a], 1u);
    a = k.y - lo; if ((unsigned)a < (unsigned)CHK) atomicAdd(&cnt[a], 1u);
    a = k.z - lo; if ((unsigned)a < (unsigned)CHK) atomicAdd(&cnt[a], 1u);
    a = k.w - lo; if ((unsigned)a < (unsigned)CHK) atomicAdd(&cnt[a], 1u);
  }
  __syncthreads();
  unsigned* p = partials + (long)sl * NN + lo;
  for (int i = threadIdx.x; i < CHK; i += 256) p[i] = cnt[i];
}

__global__ __launch_bounds__(256) void reduce_deg_kernel(
    const unsigned* __restrict__ pd, const unsigned* __restrict__ ps,
    int* __restrict__ indeg, float* __restrict__ inv_mean,
    float* __restrict__ inv_in, float* __restrict__ inv_out) {
  int n = blockIdx.x * 256 + threadIdx.x;
  if (n >= NN) return;
  unsigned di = 0, dz = 0;
  #pragma unroll 8
  for (int sl = 0; sl < NSL; ++sl) {
    di += pd[(long)sl * NN + n];
    dz += ps[(long)sl * NN + n];
  }
  indeg[n] = (int)di;
  float fdi = fmaxf((float)di, 1.f), fdz = fmaxf((float)dz, 1.f);
  inv_mean[n] = 1.f / fdi;
  inv_in[n]  = rsqrtf(fdi);
  inv_out[n] = rsqrtf(fdz);
}

__global__ __launch_bounds__(256) void scan_block_kernel(const int* __restrict__ counts,
                                                         int* excl, int* bsum, int n) {
  __shared__ int sh[256];
  int i = blockIdx.x * 256 + threadIdx.x;
  int v = (i < n) ? counts[i] : 0;
  sh[threadIdx.x] = v;
  __syncthreads();
  #pragma unroll
  for (int off = 1; off < 256; off <<= 1) {
    int tv = (threadIdx.x >= off) ? sh[threadIdx.x - off] : 0;
    __syncthreads();
    sh[threadIdx.x] += tv;
    __syncthreads();
  }
  if (i < n) excl[i] = sh[threadIdx.x] - v;
  if (threadIdx.x == 255 && bsum) bsum[blockIdx.x] = sh[255];
}

// builds per-(slice,node) cursors AND packed nodeinfo {e0, end, inv_mean, inv_in}
__global__ void cursor_init_kernel(const int* __restrict__ row_ptr, const int* __restrict__ bsum,
                                   const unsigned* __restrict__ pd,
                                   unsigned* __restrict__ cur0,
                                   const float* __restrict__ inv_mean,
                                   const float* __restrict__ inv_in,
                                   int4* __restrict__ nodeinfo) {
  int n = blockIdx.x * 256 + threadIdx.x;
  if (n >= NN) return;
  unsigned start = (unsigned)(row_ptr[n] + bsum[n >> 8]);
  unsigned run = start;
  #pragma unroll 8
  for (int sl = 0; sl < NSL; ++sl) {
    cur0[(long)sl * NN + n] = run;
    run += pd[(long)sl * NN + n];
  }
  nodeinfo[n] = make_int4((int)start, (int)run,
                          __float_as_int(inv_mean[n]), __float_as_int(inv_in[n]));
}

__global__ __launch_bounds__(256) void fill_partial_kernel(
    const int4* __restrict__ dst4, const int4* __restrict__ src4,
    const unsigned* __restrict__ cur0, int* __restrict__ col) {
  __shared__ unsigned cur[CHK];
  const int chunk = blockIdx.x & 3;
  const int sl = blockIdx.x >> 2;
  const int lo = chunk * CHK;
  const unsigned* c0 = cur0 + (long)sl * NN + lo;
  for (int i = threadIdx.x; i < CHK; i += 256) cur[i] = c0[i];
  __syncthreads();
  const int base4 = sl * (ESL / 4);
  for (int i = threadIdx.x; i < ESL / 4; i += 256) {
    int4 d = dst4[base4 + i];
    int4 s = src4[base4 + i];
    int a;
    a = d.x - lo; if ((unsigned)a < (unsigned)CHK) col[atomicAdd(&cur[a], 1u)] = s.x;
    a = d.y - lo; if ((unsigned)a < (unsigned)CHK) col[atomicAdd(&cur[a], 1u)] = s.y;
    a = d.z - lo; if ((unsigned)a < (unsigned)CHK) col[atomicAdd(&cur[a], 1u)] = s.z;
    a = d.w - lo; if ((unsigned)a < (unsigned)CHK) col[atomicAdd(&cur[a], 1u)] = s.w;
  }
}

// ---------------- SpMM over feature-sliced fp16 table (2 slices x 64 feats) ----------------
// X16 layout: [slice=2][node][64] __half (128B rows, 6.4MB/slice; slice pinned
// to XCD-quad via blockIdx&7). Wave = one (node, slice); lane = e8*8 + q8:
// 8 edges x 16B (row covered by 8 consecutive lanes). 16 edges/iter via two
// independent 8-edge groups. Reduce: 3-level xor tree x 8 accs.

__global__ __launch_bounds__(256) void spmm64s_kernel(
    const int4* __restrict__ nodeinfo, const int* __restrict__ cols,
    const __half* __restrict__ xs, int useW,
    float* __restrict__ out) {
  const int t = threadIdx.x;
  const int lane = t & 63;
  const int wv = t >> 6;
  const int b = blockIdx.x;
  const int xcd = b & 7;
  const int slice = xcd >> 2;
  const int sub = xcd & 3;
  const int node = (b >> 3) * 16 + wv * 4 + sub;   // exact cover: NN = 3125*16
  const int q8 = lane & 7;       // 16B chunk of the 128B row
  const int e8 = lane >> 3;      // edge slot within group of 8
  const __half* xb = xs + (long)slice * NN * 64 + q8 * 8;
  int4 ni = nodeinfo[node];
  const int e0 = ni.x, end = ni.y;
  const float d = __int_as_float(useW ? ni.w : ni.z);
  const int end1 = end - 1;
  float a0 = 0.f, a1 = 0.f, a2 = 0.f, a3 = 0.f, a4 = 0.f, a5 = 0.f, a6 = 0.f, a7 = 0.f;
  float c0 = 0.f, c1 = 0.f, c2 = 0.f, c3 = 0.f, c4 = 0.f, c5 = 0.f, c6 = 0.f, c7 = 0.f;
  for (int e = e0; e < end; e += 16) {
    int ee0 = e + e8;
    int ee1 = ee0 + 8;
    int ec0 = ee0 < end ? ee0 : end1;
    int ec1 = ee1 < end ? ee1 : end1;
    int s0 = cols[ec0];
    int s1 = cols[ec1];
    float m0 = ee0 < end ? 1.f : 0.f;
    float m1 = ee1 < end ? 1.f : 0.f;
    f32x4 v0 = *(const f32x4*)(xb + (unsigned)s0 * 64u);
    f32x4 v1 = *(const f32x4*)(xb + (unsigned)s1 * 64u);
    const __half2* h0 = (const __half2*)&v0;
    const __half2* h1 = (const __half2*)&v1;
    float2 f0 = __half22float2(h0[0]), f1 = __half22float2(h0[1]);
    float2 f2 = __half22float2(h0[2]), f3 = __half22float2(h0[3]);
    float2 g0 = __half22float2(h1[0]), g1 = __half22float2(h1[1]);
    float2 g2 = __half22float2(h1[2]), g3 = __half22float2(h1[3]);
    a0 = fmaf(f0.x, m0, a0); a1 = fmaf(f0.y, m0, a1);
    a2 = fmaf(f1.x, m0, a2); a3 = fmaf(f1.y, m0, a3);
    a4 = fmaf(f2.x, m0, a4); a5 = fmaf(f2.y, m0, a5);
    a6 = fmaf(f3.x, m0, a6); a7 = fmaf(f3.y, m0, a7);
    c0 = fmaf(g0.x, m1, c0); c1 = fmaf(g0.y, m1, c1);
    c2 = fmaf(g1.x, m1, c2); c3 = fmaf(g1.y, m1, c3);
    c4 = fmaf(g2.x, m1, c4); c5 = fmaf(g2.y, m1, c5);
    c6 = fmaf(g3.x, m1, c6); c7 = fmaf(g3.y, m1, c7);
  }
  a0 += c0; a1 += c1; a2 += c2; a3 += c3;
  a4 += c4; a5 += c5; a6 += c6; a7 += c7;
  #pragma unroll
  for (int m = 8; m < 64; m <<= 1) {
    a0 += __shfl_xor(a0, m, 64); a1 += __shfl_xor(a1, m, 64);
    a2 += __shfl_xor(a2, m, 64); a3 += __shfl_xor(a3, m, 64);
    a4 += __shfl_xor(a4, m, 64); a5 += __shfl_xor(a5, m, 64);
    a6 += __shfl_xor(a6, m, 64); a7 += __shfl_xor(a7, m, 64);
  }
  if (lane < 8) {
    float* op = out + (long)node * HF + slice * 64 + q8 * 8;
    *(f32x4*)op       = (f32x4){a0 * d, a1 * d, a2 * d, a3 * d};
    *(f32x4*)(op + 4) = (f32x4){a4 * d, a5 * d, a6 * d, a7 * d};
  }
}

// ---------------- attention gate + gated residual ----------------

__global__ __launch_bounds__(128) void attn_hatt_kernel(
    const float* __restrict__ a, const float* __restrict__ w2, const float* __restrict__ b2,
    const float* __restrict__ h0, const float* __restrict__ agg,
    const float* __restrict__ inv_out,
    __half* __restrict__ hatt16) {
  int r = blockIdx.x, f = threadIdx.x;
  long idx = (long)r * HF + f;
  float v = a[idx] * w2[f];
  #pragma unroll
  for (int off = 32; off >= 1; off >>= 1) v += __shfl_down(v, off, 64);
  __shared__ float red[2];
  if ((f & 63) == 0) red[f >> 6] = v;
  __syncthreads();
  float dot = red[0] + red[1] + b2[0];
  float s = 1.f / (1.f + __expf(-dot));
  float h = h0[idx] + agg[idx] * s;
  hatt16[((long)(f >> 6) * NN + r) * 64 + (f & 63)] = __float2half(h * inv_out[r]);
}

// ---------------- weight prepack: fp32 W[K][N] -> bf16 hi/lo MFMA fragments ----------------

__global__ void prepack_kernel(const float* __restrict__ W, int N, int ldw, int NTpad,
                               ushort* __restrict__ hi, ushort* __restrict__ lo, int total) {
  int idx = blockIdx.x * 256 + threadIdx.x;
  if (idx >= total) return;
  int j    = idx & 7;
  int lane = (idx >> 3) & 63;
  int rest = idx >> 9;
  int nt = rest % NTpad;
  int kc = rest / NTpad;
  int k = kc * 32 + (lane >> 4) * 8 + j;
  int n = nt * 16 + (lane & 15);
  float w = (n < N) ? W[(long)k * ldw + n] : 0.f;
  ushort h = f2bf(w);
  hi[idx] = h;
  lo[idx] = f2bf(w - bf2f(h));
}

// ---------------- split-bf16 MFMA GEMM: out = epi( [A1|A2] @ W + bias ) ----------------
// 64-row x NT*16-col tile, 4 waves; each wave 16 rows x NT*16 cols.
// 782 blocks -> ~12 waves/CU for latency hiding. fp32 A, split in-loop.

template<int KC, int NT, int EPI, int H16>
__global__ __launch_bounds__(256) void mgemm_kernel(
    const float* __restrict__ A1, int lda1,
    const float* __restrict__ A2, int lda2,
    const ushort* __restrict__ Bhi, const ushort* __restrict__ Blo,
    const float* __restrict__ bias,
    const float* __restrict__ g, const float* __restrict__ be,
    const float* __restrict__ mu, const float* __restrict__ va,
    const float* __restrict__ res,
    float* __restrict__ out, int ldc, int Ncols,
    __half* __restrict__ out16, const float* __restrict__ rowscale) {
  const int t = threadIdx.x;
  const int lane = t & 63;
  const int wid = t >> 6;
  const int rowbase = blockIdx.x * 64 + wid * 16;
  const int arow = rowbase + (lane & 15);
  const int kgrp = (lane >> 4) * 8;

  f32x4 acc[NT];
  #pragma unroll
  for (int n = 0; n < NT; ++n) acc[n] = (f32x4){0.f, 0.f, 0.f, 0.f};

  for (int kc = 0; kc < KC; ++kc) {
    const bool second = (KC == 8) && (kc >= 4);
    const float* Ap = second ? A2 : A1;
    const int lda = second ? lda2 : lda1;
    const long kb = (long)(second ? (kc - 4) * 32 : kc * 32) + kgrp;

    const f32x4 z4 = {0.f, 0.f, 0.f, 0.f};
    f32x4 ava = z4, avb = z4;
    if (arow < NN) {
      const float* p = Ap + (long)arow * lda + kb;
      ava = *(const f32x4*)p;
      avb = *(const f32x4*)(p + 4);
    }

    bf16x8 ah, al;
    #pragma unroll
    for (int j = 0; j < 8; ++j) {
      float v0 = (j < 4) ? ava[j] : avb[j - 4];
      ushort h0 = f2bf(v0);
      ah[j] = (short)h0;
      al[j] = (short)f2bf(v0 - bf2f(h0));
    }

    const ushort* bh = Bhi + ((long)kc * NT * 64 + lane) * 8;
    const ushort* bl = Blo + ((long)kc * NT * 64 + lane) * 8;
    #pragma unroll
    for (int nt = 0; nt < NT; ++nt) {
      bf16x8 bhv = *(const bf16x8*)(bh + (long)nt * 512);
      bf16x8 blv = *(const bf16x8*)(bl + (long)nt * 512);
      acc[nt] = __builtin_amdgcn_mfma_f32_16x16x32_bf16(ah, bhv, acc[nt], 0, 0, 0);
      acc[nt] = __builtin_amdgcn_mfma_f32_16x16x32_bf16(al, bhv, acc[nt], 0, 0, 0);
      acc[nt] = __builtin_amdgcn_mfma_f32_16x16x32_bf16(ah, blv, acc[nt], 0, 0, 0);
    }
  }

  const int colg = lane & 15;
  const int rsub = (lane >> 4) * 4;
  #pragma unroll
  for (int nt = 0; nt < NT; ++nt) {
    int c = nt * 16 + colg;
    if (c >= Ncols) continue;
    float bb = bias ? bias[c] : 0.f;
    float scale = 1.f, shift = 0.f;
    if (EPI == EPI_BN || EPI == EPI_BN_RES) {
      scale = g[c] * rsqrtf(va[c] + EPSV);
      shift = be[c] - mu[c] * scale;
    }
    #pragma unroll
    for (int i = 0; i < 4; ++i) {
      int r = rowbase + rsub + i;
      if (r >= NN) continue;
      float v = acc[nt][i] + bb;
      if (EPI == EPI_RELU) {
        v = fmaxf(v, 0.f);
      } else if (EPI == EPI_BN || EPI == EPI_BN_RES) {
        v = fmaxf(v * scale + shift, 0.f);
        if (EPI == EPI_BN_RES) v += res[(long)r * HF + c];
      }
      out[(long)r * ldc + c] = v;
      if (H16 != H16_NONE) {
        float sc = (H16 == H16_SCALED) ? rowscale[r] : 1.f;
        out16[((long)(nt >> 2) * NN + r) * 64 + (nt & 3) * 16 + colg] = __float2half(v * sc);
      }
    }
  }
}

// ---------------- launch ----------------

extern "C" void kernel_launch(void* const* d_in, const int* in_sizes, int n_in,
                              void* d_out, int out_size, void* d_ws, size_t ws_size,
                              hipStream_t stream) {
  const float* features = (const float*)d_in[0];
  const int*   src      = (const int*)d_in[1];
  const int*   dst      = (const int*)d_in[2];
  const float* w_in     = (const float*)d_in[3];
  const float* b_in     = (const float*)d_in[4];
  const float* gc_w     = (const float*)d_in[5];
  const float* gc_b     = (const float*)d_in[6];
  const float* bn_gamma = (const float*)d_in[7];
  const float* bn_beta  = (const float*)d_in[8];
  const float* bn_mean  = (const float*)d_in[9];
  const float* bn_var   = (const float*)d_in[10];
  const float* attn_w1  = (const float*)d_in[11];
  const float* attn_b1  = (const float*)d_in[12];
  const float* attn_w2  = (const float*)d_in[13];
  const float* attn_b2  = (const float*)d_in[14];
  const float* agg_w    = (const float*)d_in[15];
  const float* agg_b    = (const float*)d_in[16];
  const float* out_w    = (const float*)d_in[17];
  const float* out_b    = (const float*)d_in[18];
  float* out = (float*)d_out;

  float* fbase   = (float*)d_ws;
  float* W0 = fbase;                 // h0 -> spmm scratch
  float* W1 = fbase + NH;            // neigh -> a -> h(L0 res home, see below)
  float* W2 = fbase + 2 * NH;        // agg -> rst0 -> rst2
  float* inv_mean = fbase + 3 * NH;
  float* inv_in   = inv_mean + NN;
  float* inv_out  = inv_in + NN;
  int* indeg   = (int*)(inv_out + NN);
  int* row_ptr = indeg + NN;         // NN+16
  int* bsum    = row_ptr + NN + 16;  // 256
  int* col     = bsum + 256;         // EE
  int4* nodeinfo = (int4*)(col + EE);

  // preprocessing scratch aliased into W1/W2 (dead before their first writes)
  unsigned* pd   = (unsigned*)W1;
  unsigned* ps   = pd + (long)NSL * NN;
  unsigned* cur0 = ps + (long)NSL * NN;

  // packed bf16 hi/lo weights
  ushort* pk = (ushort*)(nodeinfo + NN);
  const int SZ256 = 8 * 8 * 512;     // K=256, NT=8
  const int SZ128 = 4 * 8 * 512;     // K=128, NT=8
  const int SZOUT = 4 * 4 * 512;     // K=128, NT=4
  ushort* win_hi = pk;  pk += SZ256;  ushort* win_lo = pk;  pk += SZ256;
  ushort* agg_hi = pk;  pk += SZ256;  ushort* agg_lo = pk;  pk += SZ256;
  ushort* at1_hi = pk;  pk += SZ256;  ushort* at1_lo = pk;  pk += SZ256;
  ushort* gch[3], *gcl[3];
  for (int i = 0; i < 3; ++i) { gch[i] = pk; pk += SZ128; gcl[i] = pk; pk += SZ128; }
  ushort* ow_hi = pk;  pk += SZOUT;   ushort* ow_lo = pk;  pk += SZOUT;
  __half* X16 = (__half*)pk;          // NH halfs, sliced [2][NN][64]

  dim3 b256(256), b128(128);
  const int gN = (NN + 255) / 256;
  const int gblocks = (NN + 63) / 64;     // 782
  const int gspmm = (NN / 16) * 8;        // 25000
  const int gpre = NSL * 4;

  // graph preprocessing (no global atomics)
  count_partial_kernel<<<gpre, b256, 0, stream>>>((const int4*)dst, pd);
  count_partial_kernel<<<gpre, b256, 0, stream>>>((const int4*)src, ps);
  reduce_deg_kernel<<<gN, b256, 0, stream>>>(pd, ps, indeg, inv_mean, inv_in, inv_out);
  scan_block_kernel<<<gN, b256, 0, stream>>>(indeg, row_ptr, bsum, NN);
  scan_block_kernel<<<1, b256, 0, stream>>>(bsum, bsum, nullptr, gN);
  cursor_init_kernel<<<gN, b256, 0, stream>>>(row_ptr, bsum, pd, cur0, inv_mean, inv_in, nodeinfo);
  fill_partial_kernel<<<gpre, b256, 0, stream>>>((const int4*)dst, (const int4*)src, cur0, col);

  // weight prepack
  prepack_kernel<<<(SZ256 + 255) / 256, b256, 0, stream>>>(w_in,    HF, HF, 8, win_hi, win_lo, SZ256);
  prepack_kernel<<<(SZ256 + 255) / 256, b256, 0, stream>>>(agg_w,   HF, HF, 8, agg_hi, agg_lo, SZ256);
  prepack_kernel<<<(SZ256 + 255) / 256, b256, 0, stream>>>(attn_w1, HF, HF, 8, at1_hi, at1_lo, SZ256);
  for (int i = 0; i < 3; ++i)
    prepack_kernel<<<(SZ128 + 255) / 256, b256, 0, stream>>>(gc_w + (long)i * HF * HF, HF, HF, 8, gch[i], gcl[i], SZ128);
  prepack_kernel<<<(SZOUT + 255) / 256, b256, 0, stream>>>(out_w, CC, CC, 4, ow_hi, ow_lo, SZOUT);

  // h0 = relu(features @ w_in + b_in)            -> W0 (+fp16 raw sliced -> X16)
  mgemm_kernel<8, 8, EPI_RELU, H16_RAW><<<gblocks, b256, 0, stream>>>(
      features, INF_, features + 128, INF_, win_hi, win_lo, b_in,
      nullptr, nullptr, nullptr, nullptr, nullptr, W0, HF, HF, X16, nullptr);
  // neigh = mean-agg(h0)                          -> W1
  spmm64s_kernel<<<gspmm, b256, 0, stream>>>(nodeinfo, col, X16, 0, W1);
  // agg = relu([h0|neigh] @ agg_w + agg_b)        -> W2
  mgemm_kernel<8, 8, EPI_RELU, H16_NONE><<<gblocks, b256, 0, stream>>>(
      W0, HF, W1, HF, agg_hi, agg_lo, agg_b,
      nullptr, nullptr, nullptr, nullptr, nullptr, W2, HF, HF, nullptr, nullptr);
  // a = relu([h0|agg] @ attn_w1 + attn_b1)        -> W1
  mgemm_kernel<8, 8, EPI_RELU, H16_NONE><<<gblocks, b256, 0, stream>>>(
      W0, HF, W2, HF, at1_hi, at1_lo, attn_b1,
      nullptr, nullptr, nullptr, nullptr, nullptr, W1, HF, HF, nullptr, nullptr);
  // h_att = h0 + agg * sigmoid(a@w2+b2)           -> X16 (scaled by inv_out)
  attn_hatt_kernel<<<NN, b128, 0, stream>>>(W1, attn_w2, attn_b2, W0, W2, inv_out, X16);

  // layer 0: spmm(X16)->W0 ; rst0 = relu(BN(W0@gc0+b0))   -> W2 + X16
  spmm64s_kernel<<<gspmm, b256, 0, stream>>>(nodeinfo, col, X16, 1, W0);
  mgemm_kernel<4, 8, EPI_BN, H16_SCALED><<<gblocks, b256, 0, stream>>>(
      W0, HF, nullptr, 0, gch[0], gcl[0], gc_b,
      bn_gamma, bn_beta, bn_mean, bn_var, nullptr, W2, HF, HF, X16, inv_out);
  // layer 1: spmm(X16)->W0 ; rst1 = relu(BN(W0@gc1+b1)) + rst0 -> W1 + X16
  spmm64s_kernel<<<gspmm, b256, 0, stream>>>(nodeinfo, col, X16, 1, W0);
  mgemm_kernel<4, 8, EPI_BN_RES, H16_SCALED><<<gblocks, b256, 0, stream>>>(
      W0, HF, nullptr, 0, gch[1], gcl[1], gc_b + HF,
      bn_gamma + HF, bn_beta + HF, bn_mean + HF, bn_var + HF, W2, W1, HF, HF, X16, inv_out);
  // layer 2: spmm(X16)->W0 ; rst2 = relu(BN(W0@gc2+b2)) + rst1 -> W2
  spmm64s_kernel<<<gspmm, b256, 0, stream>>>(nodeinfo, col, X16, 1, W0);
  mgemm_kernel<4, 8, EPI_BN_RES, H16_NONE><<<gblocks, b256, 0, stream>>>(
      W0, HF, nullptr, 0, gch[2], gcl[2], gc_b + 2 * HF,
      bn_gamma + 2 * HF, bn_beta + 2 * HF, bn_mean + 2 * HF, bn_var + 2 * HF, W1, W2, HF, HF,
      nullptr, nullptr);

  // out = rst2 @ out_w + out_b                    -> d_out
  mgemm_kernel<4, 4, EPI_NONE, H16_NONE><<<gblocks, b256, 0, stream>>>(
      W2, HF, nullptr, 0, ow_hi, ow_lo, out_b,
      nullptr, nullptr, nullptr, nullptr, nullptr, out, CC, CC, nullptr, nullptr);
}